// Round 16
// baseline (195.690 us; speedup 1.0000x reference)
//
#include <hip/hip_runtime.h>
#include <hip/hip_bf16.h>
#include <stdint.h>

typedef unsigned short u16;
typedef __attribute__((ext_vector_type(8))) short short8;
typedef __attribute__((ext_vector_type(4))) float f32x4;

#define B_ 2
#define S_ 2048
#define D_ 1024
#define H_ 16
#define DK_ 64
// scale folded into Q: (1/sqrt(DK)) * log2(e)  -> softmax done with exp2
#define QSCALE 0.18033688011112042f

__device__ __forceinline__ u16 f2bf(float f) {
  union { float f; uint32_t u; } c; c.f = f;
  uint32_t u = c.u;
  u += 0x7fffu + ((u >> 16) & 1u);
  return (u16)(u >> 16);
}

__device__ __forceinline__ uint32_t pk_bf16(float a, float b) {
  __hip_bfloat162 h = __float22bfloat162_rn(float2{a, b});
  union { __hip_bfloat162 h; uint32_t u; } c; c.h = h;
  return c.u;
}

__device__ __forceinline__ float fexp2(float x) {
#if __has_builtin(__builtin_amdgcn_exp2f)
  return __builtin_amdgcn_exp2f(x);
#else
  return exp2f(x);
#endif
}

__device__ __forceinline__ void gll16(const void* g, void* l) {
  __builtin_amdgcn_global_load_lds(
      (const __attribute__((address_space(1))) uint32_t*)g,
      (__attribute__((address_space(3))) uint32_t*)l, 16, 0, 0);
}

// ---------------- fused prep: cast hidden + Wq/Wk/Wv transpose + bias + Wo transpose
__global__ __launch_bounds__(256) void prep_k(const float* __restrict__ hidden,
                                              const float* __restrict__ Wq,
                                              const float* __restrict__ Wk,
                                              const float* __restrict__ Wv,
                                              const float* __restrict__ bq,
                                              const float* __restrict__ bk,
                                              const float* __restrict__ bv,
                                              const float* __restrict__ Wo,
                                              u16* __restrict__ Abf,
                                              u16* __restrict__ Wt,
                                              u16* __restrict__ Wot,
                                              float* __restrict__ biasQKV) {
  __shared__ float t[64][65];
  const int bx = blockIdx.x;
  const int tid = threadIdx.x;

  if (bx < 2048) {
    int i = (bx * 256 + tid) * 8;
    float4 a = *(const float4*)(hidden + i);
    float4 b = *(const float4*)(hidden + i + 4);
    short8 o;
    o[0] = (short)f2bf(a.x); o[1] = (short)f2bf(a.y);
    o[2] = (short)f2bf(a.z); o[3] = (short)f2bf(a.w);
    o[4] = (short)f2bf(b.x); o[5] = (short)f2bf(b.y);
    o[6] = (short)f2bf(b.z); o[7] = (short)f2bf(b.w);
    *(short8*)(Abf + i) = o;
    return;
  }

  if (bx < 2816) {
    const int blk = bx - 2048;
    const int by = blk & 15, z = blk >> 4;
    const int grp = z >> 4, h = z & 15;
    const float* src = (grp == 0) ? Wq : (grp == 1) ? Wk : Wv;
    const float* bsrc = (grp == 0) ? bq : (grp == 1) ? bk : bv;
    const float scale = (grp == 0) ? QSCALE : 1.0f;
    u16* dst = Wt + (size_t)grp * 1024 * 1024;
    const float* Sp = src + (size_t)h * 1024 * 64;
    const int r0 = by * 64;
#pragma unroll
    for (int i = 0; i < 4; i++) {
      int r = i * 16 + (tid >> 4), c = (tid & 15) * 4;
      float4 v = *(const float4*)(Sp + (size_t)(r0 + r) * 64 + c);
      t[r][c] = v.x; t[r][c + 1] = v.y; t[r][c + 2] = v.z; t[r][c + 3] = v.w;
    }
    if (by == 0 && tid < 64)
      biasQKV[grp * 1024 + h * 64 + tid] = bsrc[h * 64 + tid] * scale;
    __syncthreads();
#pragma unroll
    for (int i = 0; i < 4; i++) {
      int c = i * 16 + (tid >> 4), r = (tid & 15) * 4;
      ushort4 o;
      o.x = f2bf(t[r][c] * scale);
      o.y = f2bf(t[r + 1][c] * scale);
      o.z = f2bf(t[r + 2][c] * scale);
      o.w = f2bf(t[r + 3][c] * scale);
      *(ushort4*)(dst + (size_t)(h * 64 + c) * 1024 + r0 + r) = o;
    }
    return;
  }

  {
    const int blk = bx - 2816;
    const int c0 = (blk & 15) * 64, r0 = (blk >> 4) * 64;
#pragma unroll
    for (int i = 0; i < 4; i++) {
      int r = i * 16 + (tid >> 4), c = (tid & 15) * 4;
      float4 v = *(const float4*)(Wo + (size_t)(r0 + r) * 1024 + c0 + c);
      t[r][c] = v.x; t[r][c + 1] = v.y; t[r][c + 2] = v.z; t[r][c + 3] = v.w;
    }
    __syncthreads();
#pragma unroll
    for (int i = 0; i < 4; i++) {
      int c = i * 16 + (tid >> 4), r = (tid & 15) * 4;
      ushort4 o;
      o.x = f2bf(t[r][c]);
      o.y = f2bf(t[r + 1][c]);
      o.z = f2bf(t[r + 2][c]);
      o.w = f2bf(t[r + 3][c]);
      *(ushort4*)(Wot + (size_t)(c0 + c) * 1024 + r0 + r) = o;
    }
  }
}

// ---------------- QKV GEMM 128x128, R18: dbuf + COUNTED vmcnt (T4) -----------
// R18 WIN (195.5us total, -6 vs R12): raw s_barrier + counted s_waitcnt
// vmcnt(8) keeps the 8 prefetch gll16s in flight across both barriers
// (AITER/T4 pattern; __syncthreads' vmcnt(0) drain was the stall).
// Race audit: barrier-after-compute ensures all waves' ds_reads of a buffer
// complete before next stage overwrites it; vmcnt(8)+barrier ensures all
// waves' cur-tile gll16s landed before any ds_read. sched_barrier(0) pins
// ordering (rule 18). LDS 64KB -> 2 blocks/CU. V-fused epilogue unchanged.
__global__ __launch_bounds__(256) void gemm_bt_k(const u16* __restrict__ A,
                                                 const u16* __restrict__ B,
                                                 const float* __restrict__ bias,
                                                 u16* __restrict__ Cout,
                                                 u16* __restrict__ Vt,
                                                 int M, int N, int K) {
  __shared__ u16 As[2][128 * 64];
  __shared__ u16 Bs[2][128 * 64];
  const int tid = threadIdx.x;
  const int w = tid >> 6, lane = tid & 63;
  const int wm = w >> 1, wn = w & 1;
  const int orig = blockIdx.x;
  const int xcd = orig & 7, idx = orig >> 3;
  const int ni = idx >> 2, mi_ = idx & 3;
  const int m0 = (xcd * 4 + mi_) * 128, n0 = ni * 128;
  const int l15 = lane & 15, quad = lane >> 4;
  const int colr[2] = {(((quad) ^ (l15 & 7)) & 7) * 8,
                       (((4 + quad) ^ (l15 & 7)) & 7) * 8};

  int r_st[4], cs_st[4];
#pragma unroll
  for (int i = 0; i < 4; i++) {
    int idx2 = i * 256 + tid;
    r_st[i] = idx2 >> 3;
    cs_st[i] = ((idx2 & 7) ^ (r_st[i] & 7)) * 8;
  }

  f32x4 acc[4][4];
  const f32x4 zero = {0.f, 0.f, 0.f, 0.f};
#pragma unroll
  for (int i = 0; i < 4; i++)
#pragma unroll
    for (int j = 0; j < 4; j++) acc[i][j] = zero;

  auto stage = [&](int bb, int k0) {
#pragma unroll
    for (int i = 0; i < 4; i++) {
      gll16(A + (size_t)(m0 + r_st[i]) * K + k0 + cs_st[i], &As[bb][(i * 256 + w * 64) * 8]);
      gll16(B + (size_t)(n0 + r_st[i]) * K + k0 + cs_st[i], &Bs[bb][(i * 256 + w * 64) * 8]);
    }
  };

  auto compute = [&](int bb) {
#pragma unroll
    for (int kk = 0; kk < 2; kk++) {
      short8 af[4], bf[4];
#pragma unroll
      for (int i = 0; i < 4; i++) {
        af[i] = *(const short8*)&As[bb][(wm * 64 + i * 16 + l15) * 64 + colr[kk]];
        bf[i] = *(const short8*)&Bs[bb][(wn * 64 + i * 16 + l15) * 64 + colr[kk]];
      }
#pragma unroll
      for (int mi = 0; mi < 4; mi++)
#pragma unroll
        for (int ni2 = 0; ni2 < 4; ni2++)
          acc[mi][ni2] = __builtin_amdgcn_mfma_f32_16x16x32_bf16(af[mi], bf[ni2], acc[mi][ni2], 0, 0, 0);
    }
  };

  stage(0, 0);
  int cur = 0;
  for (int t = 0; t < 15; t++) {
    stage(cur ^ 1, (t + 1) * 64);              // 8 prefetch loads issued
    asm volatile("s_waitcnt vmcnt(8)" ::: "memory");  // cur tile landed; prefetch in flight
    __builtin_amdgcn_sched_barrier(0);
    __builtin_amdgcn_s_barrier();              // all waves' cur loads done
    compute(cur);
    __builtin_amdgcn_sched_barrier(0);
    __builtin_amdgcn_s_barrier();              // all waves done reading cur
    cur ^= 1;
  }
  asm volatile("s_waitcnt vmcnt(0)" ::: "memory");
  __builtin_amdgcn_sched_barrier(0);
  __builtin_amdgcn_s_barrier();
  compute(cur);

  const int cm = m0 + wm * 64, cn = n0 + wn * 64;
  if (n0 < 2048) {
    // Q/K region: row-major write into qkv
#pragma unroll
    for (int ni2 = 0; ni2 < 4; ni2++) {
      int n = cn + ni2 * 16 + l15;
      float bv = bias[n];
#pragma unroll
      for (int mi = 0; mi < 4; mi++) {
#pragma unroll
        for (int r = 0; r < 4; r++) {
          int m = cm + mi * 16 + quad * 4 + r;
          Cout[(size_t)m * N + n] = f2bf(acc[mi][ni2][r] + bv);
        }
      }
    }
  } else {
    // V region: write transposed directly to Vt [b][h][v][s]
    const int bidx = m0 >> 11;        // batch (block-uniform; 2048 % 128 == 0)
    const int sbase = (cm & 2047) + quad * 4;
#pragma unroll
    for (int ni2 = 0; ni2 < 4; ni2++) {
      const int n = cn + ni2 * 16 + l15;
      const int vg = n - 2048;        // h*64 + v
      const float bv = bias[n];
      u16* vbase = Vt + (size_t)(bidx * 1024 + vg) * 2048 + sbase;
#pragma unroll
      for (int mi = 0; mi < 4; mi++) {
        ushort4 pk;
        pk.x = f2bf(acc[mi][ni2][0] + bv);
        pk.y = f2bf(acc[mi][ni2][1] + bv);
        pk.z = f2bf(acc[mi][ni2][2] + bv);
        pk.w = f2bf(acc[mi][ni2][3] + bv);
        *(ushort4*)(vbase + mi * 16) = pk;
      }
    }
  }
}

// ---------------- GEMM 64x128, R19: dbuf + COUNTED vmcnt (T4, count=6) -------
// Neutral vs R12's __syncthreads dbuf (within noise) but kept: same proven
// race structure as R18, and never drains the prefetch queue.
__global__ __launch_bounds__(256) void gemm_bt64_k(const u16* __restrict__ A,
                                                   const u16* __restrict__ B,
                                                   const float* __restrict__ bias,
                                                   float* __restrict__ Cout,
                                                   int M, int N, int K) {
  __shared__ u16 As[2][64 * 64];
  __shared__ u16 Bs[2][128 * 64];
  const int tid = threadIdx.x;
  const int w = tid >> 6, lane = tid & 63;
  const int wm = w >> 1, wn = w & 1;
  const int orig = blockIdx.x;
  const int xcd = orig & 7, idx = orig >> 3;
  const int ni = idx >> 3, mi_ = idx & 7;
  const int m0 = (xcd * 8 + mi_) * 64, n0 = ni * 128;
  const int l15 = lane & 15, quad = lane >> 4;
  const int colr[2] = {(((quad) ^ (l15 & 7)) & 7) * 8,
                       (((4 + quad) ^ (l15 & 7)) & 7) * 8};

  // A: 64x64 = 4096 u16 -> 2 rounds; B: 128x64 = 8192 u16 -> 4 rounds
  int rA[2], cA[2], rB[4], cB[4];
#pragma unroll
  for (int i = 0; i < 2; i++) {
    int idx2 = i * 256 + tid;
    rA[i] = idx2 >> 3;
    cA[i] = ((idx2 & 7) ^ (rA[i] & 7)) * 8;
  }
#pragma unroll
  for (int i = 0; i < 4; i++) {
    int idx2 = i * 256 + tid;
    rB[i] = idx2 >> 3;
    cB[i] = ((idx2 & 7) ^ (rB[i] & 7)) * 8;
  }

  f32x4 acc[2][4];
  const f32x4 zero = {0.f, 0.f, 0.f, 0.f};
#pragma unroll
  for (int i = 0; i < 2; i++)
#pragma unroll
    for (int j = 0; j < 4; j++) acc[i][j] = zero;

  auto stage = [&](int bb, int k0) {
#pragma unroll
    for (int i = 0; i < 2; i++)
      gll16(A + (size_t)(m0 + rA[i]) * K + k0 + cA[i], &As[bb][(i * 256 + w * 64) * 8]);
#pragma unroll
    for (int i = 0; i < 4; i++)
      gll16(B + (size_t)(n0 + rB[i]) * K + k0 + cB[i], &Bs[bb][(i * 256 + w * 64) * 8]);
  };

  auto compute = [&](int bb) {
#pragma unroll
    for (int kk = 0; kk < 2; kk++) {
      short8 af[2], bf[4];
#pragma unroll
      for (int i = 0; i < 2; i++)
        af[i] = *(const short8*)&As[bb][(wm * 32 + i * 16 + l15) * 64 + colr[kk]];
#pragma unroll
      for (int j = 0; j < 4; j++)
        bf[j] = *(const short8*)&Bs[bb][(wn * 64 + j * 16 + l15) * 64 + colr[kk]];
#pragma unroll
      for (int i = 0; i < 2; i++)
#pragma unroll
        for (int j = 0; j < 4; j++)
          acc[i][j] = __builtin_amdgcn_mfma_f32_16x16x32_bf16(af[i], bf[j], acc[i][j], 0, 0, 0);
    }
  };

  stage(0, 0);
  int cur = 0;
  for (int t = 0; t < 15; t++) {
    stage(cur ^ 1, (t + 1) * 64);              // 6 prefetch loads issued
    asm volatile("s_waitcnt vmcnt(6)" ::: "memory");  // cur tile landed; prefetch in flight
    __builtin_amdgcn_sched_barrier(0);
    __builtin_amdgcn_s_barrier();              // all waves' cur loads done
    compute(cur);
    __builtin_amdgcn_sched_barrier(0);
    __builtin_amdgcn_s_barrier();              // all waves done reading cur
    cur ^= 1;
  }
  asm volatile("s_waitcnt vmcnt(0)" ::: "memory");
  __builtin_amdgcn_sched_barrier(0);
  __builtin_amdgcn_s_barrier();
  compute(cur);

  const int cm = m0 + wm * 32, cn = n0 + wn * 64;
#pragma unroll
  for (int j = 0; j < 4; j++) {
    int n = cn + j * 16 + l15;
    float bv = bias[n];
#pragma unroll
    for (int i = 0; i < 2; i++) {
#pragma unroll
      for (int r = 0; r < 4; r++) {
        int m = cm + i * 16 + quad * 4 + r;
        Cout[(size_t)m * N + n] = acc[i][j][r] + bv;
      }
    }
  }
}

// ---------------- flash attention (R20: counted-vmcnt two-barrier, T4) -------
// R19 structure issued stage(t+1) only AFTER the __syncthreads drain of
// stage(t). R20 applies the R18 transformation: stage(t+1) issued BEFORE the
// counted wait for stage(t) -> each prefetch gains an extra wait-phase of
// lead time (covers cold HBM first-touches of each (b,h)'s K/V, ~900cy >
// one compute phase). vmcnt(4): after issuing stage(t+1)'s 4, outstanding=8;
// wait until <=4 retires exactly stage(t)'s 4 (oldest). Trailing barrier
// protects buf (t+1)&1 from overwrite before compute(t-1) readers done —
// identical race structure proven in R18 (gemm_bt) and R19 (gemm64).
__global__ __launch_bounds__(256, 4) void attn_k(const u16* __restrict__ qkv,
                                                 const u16* __restrict__ Vt,
                                                 u16* __restrict__ ctx) {
  __shared__ u16 Ks[2][64 * 64];
  __shared__ u16 Vs[2][64 * 64];
  const int tid = threadIdx.x;
  const int w = tid >> 6, lane = tid & 63;
  const int wq = w >> 1, wk = w & 1;
  const int l15 = lane & 15, quad = lane >> 4;

  // XCD-aware remap: xcd = orig%8 (dispatch round-robin); each xcd gets a
  // contiguous swz-range of 128 = 4 complete (b,h) groups of 32 q-blocks.
  const int orig = blockIdx.x;
  const int swz = (orig & 7) * 128 + (orig >> 3);
  const int q0 = (swz & 31) * 64;
  const int bh = swz >> 5;
  const int h = bh & 15, b = bh >> 4;

  short8 qf[2][2];
#pragma unroll
  for (int rt = 0; rt < 2; rt++) {
    const u16* qbase = qkv + (size_t)(b * S_ + q0 + wq * 32 + rt * 16 + l15) * 3072 + h * 64;
    qf[rt][0] = *(const short8*)(qbase + quad * 8);
    qf[rt][1] = *(const short8*)(qbase + 32 + quad * 8);
  }

  const int col0 = ((quad ^ (l15 & 7)) & 7) * 8;
  const int col1 = (((4 + quad) ^ (l15 & 7)) & 7) * 8;
  const int colw = wk ? col1 : col0;  // this wave's s-slice of V

  int r_st[2], cs_st[2];
#pragma unroll
  for (int i = 0; i < 2; i++) {
    int idx = i * 256 + tid;
    r_st[i] = idx >> 3;
    cs_st[i] = ((idx & 7) ^ (r_st[i] & 7)) * 8;
  }
  const u16* kp[2];
  const u16* vp[2];
#pragma unroll
  for (int i = 0; i < 2; i++) {
    kp[i] = qkv + (size_t)(b * S_ + r_st[i]) * 3072 + 1024 + h * 64 + cs_st[i];
    vp[i] = Vt + ((size_t)(b * H_ + h) * 64 + r_st[i]) * S_ + cs_st[i];
  }

  const f32x4 zero = {0.f, 0.f, 0.f, 0.f};
  f32x4 o[2][4];
#pragma unroll
  for (int rt = 0; rt < 2; rt++)
#pragma unroll
    for (int i = 0; i < 4; i++) o[rt][i] = zero;
  float lsum[2] = {0.f, 0.f};

  auto stage = [&](int bb, int t) {
#pragma unroll
    for (int i = 0; i < 2; i++) {
      gll16(kp[i] + (size_t)t * 64 * 3072, &Ks[bb][(i * 256 + w * 64) * 8]);
      gll16(vp[i] + t * 64, &Vs[bb][(i * 256 + w * 64) * 8]);
    }
  };

  auto compute = [&](int bb) {
    short8 kf[2][2];
#pragma unroll
    for (int kb = 0; kb < 2; kb++) {
      const int krow = (wk * 32 + kb * 16 + l15) * 64;
      kf[kb][0] = *(const short8*)&Ks[bb][krow + col0];
      kf[kb][1] = *(const short8*)&Ks[bb][krow + col1];
    }
    short8 pf[2];
#pragma unroll
    for (int rt = 0; rt < 2; rt++) {
      uint32_t Sx[2][2];
      __builtin_amdgcn_s_setprio(1);
#pragma unroll
      for (int kb = 0; kb < 2; kb++) {
        f32x4 st = __builtin_amdgcn_mfma_f32_16x16x32_bf16(kf[kb][0], qf[rt][0], zero, 0, 0, 0);
        st = __builtin_amdgcn_mfma_f32_16x16x32_bf16(kf[kb][1], qf[rt][1], st, 0, 0, 0);
        __builtin_amdgcn_s_setprio(0);
        float p0 = fexp2(st[0]), p1 = fexp2(st[1]), p2 = fexp2(st[2]), p3 = fexp2(st[3]);
        lsum[rt] += (p0 + p1) + (p2 + p3);
        Sx[kb][0] = pk_bf16(p0, p1);  // k = kb*16 + quad*4 + {0,1}
        Sx[kb][1] = pk_bf16(p2, p3);  // k = kb*16 + quad*4 + {2,3}
      }
#pragma unroll
      for (int s = 0; s < 2; s++)
        asm volatile("v_permlane32_swap_b32 %0, %1" : "+v"(Sx[0][s]), "+v"(Sx[1][s]));
#pragma unroll
      for (int s = 0; s < 2; s++)
        asm volatile("v_permlane16_swap_b32 %0, %1" : "+v"(Sx[0][s]), "+v"(Sx[1][s]));
      union { uint32_t u[4]; short8 s8; } cv;
      cv.u[0] = Sx[0][0]; cv.u[1] = Sx[0][1];
      cv.u[2] = Sx[1][0]; cv.u[3] = Sx[1][1];
      pf[rt] = cv.s8;
    }
    __builtin_amdgcn_s_setprio(1);
#pragma unroll
    for (int vi = 0; vi < 4; vi++) {
      short8 vf = *(const short8*)&Vs[bb][(vi * 16 + l15) * 64 + colw];
      o[0][vi] = __builtin_amdgcn_mfma_f32_16x16x32_bf16(vf, pf[0], o[0][vi], 0, 0, 0);
      o[1][vi] = __builtin_amdgcn_mfma_f32_16x16x32_bf16(vf, pf[1], o[1][vi], 0, 0, 0);
    }
    __builtin_amdgcn_s_setprio(0);
  };

  stage(0, 0);
  for (int t = 0; t < 31; t++) {
    stage((t + 1) & 1, t + 1);                 // 4 prefetch loads issued
    asm volatile("s_waitcnt vmcnt(4)" ::: "memory");  // stage(t) landed; prefetch in flight
    __builtin_amdgcn_sched_barrier(0);
    __builtin_amdgcn_s_barrier();              // all waves' stage(t) loads done
    compute(t & 1);
    __builtin_amdgcn_sched_barrier(0);
    __builtin_amdgcn_s_barrier();              // all waves done reading buf t&1
  }
  asm volatile("s_waitcnt vmcnt(0)" ::: "memory");
  __builtin_amdgcn_sched_barrier(0);
  __builtin_amdgcn_s_barrier();
  compute(1);

  // ---- cross-wave (wk) reduction of O and lsum through freed LDS ----
  float ls[2];
#pragma unroll
  for (int rt = 0; rt < 2; rt++) {
    float l = lsum[rt];
    l += __shfl_xor(l, 16);
    l += __shfl_xor(l, 32);
    ls[rt] = l;
  }
  __syncthreads();  // all compute reads of Ks/Vs done before reuse
  float* red = (float*)&Ks[0][0];   // 16 KB: 2 wq-waves x 8 KB
  float* redl = (float*)&Vs[0][0];  // 1 KB
  if (wk == 1) {
#pragma unroll
    for (int rt = 0; rt < 2; rt++) {
#pragma unroll
      for (int vi = 0; vi < 4; vi++)
        *(f32x4*)(red + wq * 2048 + (rt * 4 + vi) * 256 + lane * 4) = o[rt][vi];
      redl[wq * 128 + rt * 64 + lane] = ls[rt];
    }
  }
  __syncthreads();
  if (wk == 0) {
#pragma unroll
    for (int rt = 0; rt < 2; rt++) {
      const float tot = ls[rt] + redl[wq * 128 + rt * 64 + lane];
      const float inv = 1.f / tot;
      u16* cbase = ctx + (size_t)(b * S_ + q0 + wq * 32 + rt * 16 + l15) * 1024 + h * 64;
#pragma unroll
      for (int vi = 0; vi < 4; vi++) {
        f32x4 p = *(f32x4*)(red + wq * 2048 + (rt * 4 + vi) * 256 + lane * 4);
        f32x4 s = o[rt][vi] + p;
        ushort4 pk;
        pk.x = f2bf(s[0] * inv);
        pk.y = f2bf(s[1] * inv);
        pk.z = f2bf(s[2] * inv);
        pk.w = f2bf(s[3] * inv);
        *(ushort4*)(cbase + vi * 16 + quad * 4) = pk;
      }
    }
  }
}

extern "C" void kernel_launch(void* const* d_in, const int* in_sizes, int n_in,
                              void* d_out, int out_size, void* d_ws, size_t ws_size,
                              hipStream_t stream) {
  const float* hidden = (const float*)d_in[0];
  const float* Wq = (const float*)d_in[1];
  const float* bq = (const float*)d_in[2];
  const float* Wk = (const float*)d_in[3];
  const float* bk = (const float*)d_in[4];
  const float* Wv = (const float*)d_in[5];
  const float* bv = (const float*)d_in[6];
  const float* Wo = (const float*)d_in[7];
  const float* bo = (const float*)d_in[8];
  float* out = (float*)d_out;

  char* ws = (char*)d_ws;
  u16* Abf = (u16*)(ws + 0);                 // 4096x1024 bf16   (8,388,608)
  u16* Wt = (u16*)(ws + 8388608);            // 3072x1024 bf16   (6,291,456)
  u16* Wot = (u16*)(ws + 14680064);          // 1024x1024 bf16   (2,097,152)
  float* biasQKV = (float*)(ws + 16777216);  // 3072 fp32        (12,288 padded)
  u16* qkv = (u16*)(ws + 16789504);          // 4096x3072 bf16   (25,165,824; V third unused)
  u16* Vt = (u16*)(ws + 41955328);           // [b][h][64][2048] (8,388,608)
  u16* ctx = (u16*)(ws + 50343936);          // 4096x1024 bf16   (8,388,608)

  // fused prep: cast + Wq/Wk/Wv transpose + bias + Wo transpose
  prep_k<<<3072, 256, 0, stream>>>(hidden, Wq, Wk, Wv, bq, bk, bv, Wo,
                                   Abf, Wt, Wot, biasQKV);

  // QKV projection: [4096,1024] x [3072,1024]^T -> qkv (Q,K) + Vt (V, fused
  // transpose). Flat grid 768, XCD decode inside; counted-vmcnt dbuf.
  gemm_bt_k<<<dim3(768), 256, 0, stream>>>(Abf, Wt, biasQKV, qkv, Vt, 4096, 3072, 1024);

  // flash attention -> ctx [4096, 1024] bf16 (counted-vmcnt dbuf, XCD swizzle)
  attn_k<<<dim3(1024), 256, 0, stream>>>(qkv, Vt, ctx);

  // output projection: [4096,1024] x [1024,1024]^T + bo -> fp32 out
  // (BK=64, counted-vmcnt dbuf, count=6)
  gemm_bt64_k<<<dim3(512), 256, 0, stream>>>(ctx, Wot, bo, out, 4096, 1024, 1024);
}

// Round 17
// 190.854 us; speedup vs baseline: 1.0253x; 1.0253x over previous
//
#include <hip/hip_runtime.h>
#include <hip/hip_bf16.h>
#include <stdint.h>

typedef unsigned short u16;
typedef __attribute__((ext_vector_type(8))) short short8;
typedef __attribute__((ext_vector_type(4))) float f32x4;

#define B_ 2
#define S_ 2048
#define D_ 1024
#define H_ 16
#define DK_ 64
// scale folded into Q: (1/sqrt(DK)) * log2(e)  -> softmax done with exp2
#define QSCALE 0.18033688011112042f

__device__ __forceinline__ u16 f2bf(float f) {
  union { float f; uint32_t u; } c; c.f = f;
  uint32_t u = c.u;
  u += 0x7fffu + ((u >> 16) & 1u);
  return (u16)(u >> 16);
}

__device__ __forceinline__ uint32_t pk_bf16(float a, float b) {
  __hip_bfloat162 h = __float22bfloat162_rn(float2{a, b});
  union { __hip_bfloat162 h; uint32_t u; } c; c.h = h;
  return c.u;
}

__device__ __forceinline__ float fexp2(float x) {
#if __has_builtin(__builtin_amdgcn_exp2f)
  return __builtin_amdgcn_exp2f(x);
#else
  return exp2f(x);
#endif
}

__device__ __forceinline__ void gll16(const void* g, void* l) {
  __builtin_amdgcn_global_load_lds(
      (const __attribute__((address_space(1))) uint32_t*)g,
      (__attribute__((address_space(3))) uint32_t*)l, 16, 0, 0);
}

// ---------------- fused prep: cast hidden + Wq/Wk/Wv transpose + bias + Wo transpose
__global__ __launch_bounds__(256) void prep_k(const float* __restrict__ hidden,
                                              const float* __restrict__ Wq,
                                              const float* __restrict__ Wk,
                                              const float* __restrict__ Wv,
                                              const float* __restrict__ bq,
                                              const float* __restrict__ bk,
                                              const float* __restrict__ bv,
                                              const float* __restrict__ Wo,
                                              u16* __restrict__ Abf,
                                              u16* __restrict__ Wt,
                                              u16* __restrict__ Wot,
                                              float* __restrict__ biasQKV) {
  __shared__ float t[64][65];
  const int bx = blockIdx.x;
  const int tid = threadIdx.x;

  if (bx < 2048) {
    int i = (bx * 256 + tid) * 8;
    float4 a = *(const float4*)(hidden + i);
    float4 b = *(const float4*)(hidden + i + 4);
    short8 o;
    o[0] = (short)f2bf(a.x); o[1] = (short)f2bf(a.y);
    o[2] = (short)f2bf(a.z); o[3] = (short)f2bf(a.w);
    o[4] = (short)f2bf(b.x); o[5] = (short)f2bf(b.y);
    o[6] = (short)f2bf(b.z); o[7] = (short)f2bf(b.w);
    *(short8*)(Abf + i) = o;
    return;
  }

  if (bx < 2816) {
    const int blk = bx - 2048;
    const int by = blk & 15, z = blk >> 4;
    const int grp = z >> 4, h = z & 15;
    const float* src = (grp == 0) ? Wq : (grp == 1) ? Wk : Wv;
    const float* bsrc = (grp == 0) ? bq : (grp == 1) ? bk : bv;
    const float scale = (grp == 0) ? QSCALE : 1.0f;
    u16* dst = Wt + (size_t)grp * 1024 * 1024;
    const float* Sp = src + (size_t)h * 1024 * 64;
    const int r0 = by * 64;
#pragma unroll
    for (int i = 0; i < 4; i++) {
      int r = i * 16 + (tid >> 4), c = (tid & 15) * 4;
      float4 v = *(const float4*)(Sp + (size_t)(r0 + r) * 64 + c);
      t[r][c] = v.x; t[r][c + 1] = v.y; t[r][c + 2] = v.z; t[r][c + 3] = v.w;
    }
    if (by == 0 && tid < 64)
      biasQKV[grp * 1024 + h * 64 + tid] = bsrc[h * 64 + tid] * scale;
    __syncthreads();
#pragma unroll
    for (int i = 0; i < 4; i++) {
      int c = i * 16 + (tid >> 4), r = (tid & 15) * 4;
      ushort4 o;
      o.x = f2bf(t[r][c] * scale);
      o.y = f2bf(t[r + 1][c] * scale);
      o.z = f2bf(t[r + 2][c] * scale);
      o.w = f2bf(t[r + 3][c] * scale);
      *(ushort4*)(dst + (size_t)(h * 64 + c) * 1024 + r0 + r) = o;
    }
    return;
  }

  {
    const int blk = bx - 2816;
    const int c0 = (blk & 15) * 64, r0 = (blk >> 4) * 64;
#pragma unroll
    for (int i = 0; i < 4; i++) {
      int r = i * 16 + (tid >> 4), c = (tid & 15) * 4;
      float4 v = *(const float4*)(Wo + (size_t)(r0 + r) * 1024 + c0 + c);
      t[r][c] = v.x; t[r][c + 1] = v.y; t[r][c + 2] = v.z; t[r][c + 3] = v.w;
    }
    __syncthreads();
#pragma unroll
    for (int i = 0; i < 4; i++) {
      int c = i * 16 + (tid >> 4), r = (tid & 15) * 4;
      ushort4 o;
      o.x = f2bf(t[r][c]);
      o.y = f2bf(t[r + 1][c]);
      o.z = f2bf(t[r + 2][c]);
      o.w = f2bf(t[r + 3][c]);
      *(ushort4*)(Wot + (size_t)(c0 + c) * 1024 + r0 + r) = o;
    }
  }
}

// ---------------- QKV GEMM 128x128, R18: dbuf + COUNTED vmcnt (T4) -----------
// R18 WIN (-6us vs R12): raw s_barrier + counted s_waitcnt vmcnt(8) keeps the
// 8 prefetch gll16s in flight across both barriers (AITER/T4 pattern;
// __syncthreads' vmcnt(0) drain was the stall). Race audit: barrier-after-
// compute ensures all waves' ds_reads of a buffer complete before next stage
// overwrites it; vmcnt(8)+barrier ensures all waves' cur-tile gll16s landed
// before any ds_read. sched_barrier(0) pins ordering (rule 18). LDS 64KB ->
// 2 blocks/CU. V-fused epilogue unchanged.
__global__ __launch_bounds__(256) void gemm_bt_k(const u16* __restrict__ A,
                                                 const u16* __restrict__ B,
                                                 const float* __restrict__ bias,
                                                 u16* __restrict__ Cout,
                                                 u16* __restrict__ Vt,
                                                 int M, int N, int K) {
  __shared__ u16 As[2][128 * 64];
  __shared__ u16 Bs[2][128 * 64];
  const int tid = threadIdx.x;
  const int w = tid >> 6, lane = tid & 63;
  const int wm = w >> 1, wn = w & 1;
  const int orig = blockIdx.x;
  const int xcd = orig & 7, idx = orig >> 3;
  const int ni = idx >> 2, mi_ = idx & 3;
  const int m0 = (xcd * 4 + mi_) * 128, n0 = ni * 128;
  const int l15 = lane & 15, quad = lane >> 4;
  const int colr[2] = {(((quad) ^ (l15 & 7)) & 7) * 8,
                       (((4 + quad) ^ (l15 & 7)) & 7) * 8};

  int r_st[4], cs_st[4];
#pragma unroll
  for (int i = 0; i < 4; i++) {
    int idx2 = i * 256 + tid;
    r_st[i] = idx2 >> 3;
    cs_st[i] = ((idx2 & 7) ^ (r_st[i] & 7)) * 8;
  }

  f32x4 acc[4][4];
  const f32x4 zero = {0.f, 0.f, 0.f, 0.f};
#pragma unroll
  for (int i = 0; i < 4; i++)
#pragma unroll
    for (int j = 0; j < 4; j++) acc[i][j] = zero;

  auto stage = [&](int bb, int k0) {
#pragma unroll
    for (int i = 0; i < 4; i++) {
      gll16(A + (size_t)(m0 + r_st[i]) * K + k0 + cs_st[i], &As[bb][(i * 256 + w * 64) * 8]);
      gll16(B + (size_t)(n0 + r_st[i]) * K + k0 + cs_st[i], &Bs[bb][(i * 256 + w * 64) * 8]);
    }
  };

  auto compute = [&](int bb) {
#pragma unroll
    for (int kk = 0; kk < 2; kk++) {
      short8 af[4], bf[4];
#pragma unroll
      for (int i = 0; i < 4; i++) {
        af[i] = *(const short8*)&As[bb][(wm * 64 + i * 16 + l15) * 64 + colr[kk]];
        bf[i] = *(const short8*)&Bs[bb][(wn * 64 + i * 16 + l15) * 64 + colr[kk]];
      }
#pragma unroll
      for (int mi = 0; mi < 4; mi++)
#pragma unroll
        for (int ni2 = 0; ni2 < 4; ni2++)
          acc[mi][ni2] = __builtin_amdgcn_mfma_f32_16x16x32_bf16(af[mi], bf[ni2], acc[mi][ni2], 0, 0, 0);
    }
  };

  stage(0, 0);
  int cur = 0;
  for (int t = 0; t < 15; t++) {
    stage(cur ^ 1, (t + 1) * 64);              // 8 prefetch loads issued
    asm volatile("s_waitcnt vmcnt(8)" ::: "memory");  // cur tile landed; prefetch in flight
    __builtin_amdgcn_sched_barrier(0);
    __builtin_amdgcn_s_barrier();              // all waves' cur loads done
    compute(cur);
    __builtin_amdgcn_sched_barrier(0);
    __builtin_amdgcn_s_barrier();              // all waves done reading cur
    cur ^= 1;
  }
  asm volatile("s_waitcnt vmcnt(0)" ::: "memory");
  __builtin_amdgcn_sched_barrier(0);
  __builtin_amdgcn_s_barrier();
  compute(cur);

  const int cm = m0 + wm * 64, cn = n0 + wn * 64;
  if (n0 < 2048) {
    // Q/K region: row-major write into qkv
#pragma unroll
    for (int ni2 = 0; ni2 < 4; ni2++) {
      int n = cn + ni2 * 16 + l15;
      float bv = bias[n];
#pragma unroll
      for (int mi = 0; mi < 4; mi++) {
#pragma unroll
        for (int r = 0; r < 4; r++) {
          int m = cm + mi * 16 + quad * 4 + r;
          Cout[(size_t)m * N + n] = f2bf(acc[mi][ni2][r] + bv);
        }
      }
    }
  } else {
    // V region: write transposed directly to Vt [b][h][v][s]
    const int bidx = m0 >> 11;        // batch (block-uniform; 2048 % 128 == 0)
    const int sbase = (cm & 2047) + quad * 4;
#pragma unroll
    for (int ni2 = 0; ni2 < 4; ni2++) {
      const int n = cn + ni2 * 16 + l15;
      const int vg = n - 2048;        // h*64 + v
      const float bv = bias[n];
      u16* vbase = Vt + (size_t)(bidx * 1024 + vg) * 2048 + sbase;
#pragma unroll
      for (int mi = 0; mi < 4; mi++) {
        ushort4 pk;
        pk.x = f2bf(acc[mi][ni2][0] + bv);
        pk.y = f2bf(acc[mi][ni2][1] + bv);
        pk.z = f2bf(acc[mi][ni2][2] + bv);
        pk.w = f2bf(acc[mi][ni2][3] + bv);
        *(ushort4*)(vbase + mi * 16) = pk;
      }
    }
  }
}

// ---------------- GEMM 64x128, R19: dbuf + COUNTED vmcnt (T4, count=6) -------
// Neutral vs R12's __syncthreads dbuf (within noise) but kept: same proven
// race structure as R18, and never drains the prefetch queue.
__global__ __launch_bounds__(256) void gemm_bt64_k(const u16* __restrict__ A,
                                                   const u16* __restrict__ B,
                                                   const float* __restrict__ bias,
                                                   float* __restrict__ Cout,
                                                   int M, int N, int K) {
  __shared__ u16 As[2][64 * 64];
  __shared__ u16 Bs[2][128 * 64];
  const int tid = threadIdx.x;
  const int w = tid >> 6, lane = tid & 63;
  const int wm = w >> 1, wn = w & 1;
  const int orig = blockIdx.x;
  const int xcd = orig & 7, idx = orig >> 3;
  const int ni = idx >> 3, mi_ = idx & 7;
  const int m0 = (xcd * 8 + mi_) * 64, n0 = ni * 128;
  const int l15 = lane & 15, quad = lane >> 4;
  const int colr[2] = {(((quad) ^ (l15 & 7)) & 7) * 8,
                       (((4 + quad) ^ (l15 & 7)) & 7) * 8};

  // A: 64x64 = 4096 u16 -> 2 rounds; B: 128x64 = 8192 u16 -> 4 rounds
  int rA[2], cA[2], rB[4], cB[4];
#pragma unroll
  for (int i = 0; i < 2; i++) {
    int idx2 = i * 256 + tid;
    rA[i] = idx2 >> 3;
    cA[i] = ((idx2 & 7) ^ (rA[i] & 7)) * 8;
  }
#pragma unroll
  for (int i = 0; i < 4; i++) {
    int idx2 = i * 256 + tid;
    rB[i] = idx2 >> 3;
    cB[i] = ((idx2 & 7) ^ (rB[i] & 7)) * 8;
  }

  f32x4 acc[2][4];
  const f32x4 zero = {0.f, 0.f, 0.f, 0.f};
#pragma unroll
  for (int i = 0; i < 2; i++)
#pragma unroll
    for (int j = 0; j < 4; j++) acc[i][j] = zero;

  auto stage = [&](int bb, int k0) {
#pragma unroll
    for (int i = 0; i < 2; i++)
      gll16(A + (size_t)(m0 + rA[i]) * K + k0 + cA[i], &As[bb][(i * 256 + w * 64) * 8]);
#pragma unroll
    for (int i = 0; i < 4; i++)
      gll16(B + (size_t)(n0 + rB[i]) * K + k0 + cB[i], &Bs[bb][(i * 256 + w * 64) * 8]);
  };

  auto compute = [&](int bb) {
#pragma unroll
    for (int kk = 0; kk < 2; kk++) {
      short8 af[2], bf[4];
#pragma unroll
      for (int i = 0; i < 2; i++)
        af[i] = *(const short8*)&As[bb][(wm * 32 + i * 16 + l15) * 64 + colr[kk]];
#pragma unroll
      for (int j = 0; j < 4; j++)
        bf[j] = *(const short8*)&Bs[bb][(wn * 64 + j * 16 + l15) * 64 + colr[kk]];
#pragma unroll
      for (int i = 0; i < 2; i++)
#pragma unroll
        for (int j = 0; j < 4; j++)
          acc[i][j] = __builtin_amdgcn_mfma_f32_16x16x32_bf16(af[i], bf[j], acc[i][j], 0, 0, 0);
    }
  };

  stage(0, 0);
  int cur = 0;
  for (int t = 0; t < 15; t++) {
    stage(cur ^ 1, (t + 1) * 64);              // 6 prefetch loads issued
    asm volatile("s_waitcnt vmcnt(6)" ::: "memory");  // cur tile landed; prefetch in flight
    __builtin_amdgcn_sched_barrier(0);
    __builtin_amdgcn_s_barrier();              // all waves' cur loads done
    compute(cur);
    __builtin_amdgcn_sched_barrier(0);
    __builtin_amdgcn_s_barrier();              // all waves done reading cur
    cur ^= 1;
  }
  asm volatile("s_waitcnt vmcnt(0)" ::: "memory");
  __builtin_amdgcn_sched_barrier(0);
  __builtin_amdgcn_s_barrier();
  compute(cur);

  const int cm = m0 + wm * 32, cn = n0 + wn * 64;
#pragma unroll
  for (int j = 0; j < 4; j++) {
    int n = cn + j * 16 + l15;
    float bv = bias[n];
#pragma unroll
    for (int i = 0; i < 2; i++) {
#pragma unroll
      for (int r = 0; r < 4; r++) {
        int m = cm + i * 16 + quad * 4 + r;
        Cout[(size_t)m * N + n] = acc[i][j][r] + bv;
      }
    }
  }
}

// ---------------- flash attention (R19 form — final) --------------------------
// R20's two-barrier counted-vmcnt variant was null (+0.6us): attn's staged
// loads are L2-resident (~200cy) after the XCD swizzle and already fully
// covered by one compute phase, so extra prefetch lead time buys nothing.
// Reverted to the simpler single-__syncthreads dbuf (best measured: 195.07).
// attn floor is the issue/dependency chain (VALU 48% + MFMA 24%), not loads.
__global__ __launch_bounds__(256, 4) void attn_k(const u16* __restrict__ qkv,
                                                 const u16* __restrict__ Vt,
                                                 u16* __restrict__ ctx) {
  __shared__ u16 Ks[2][64 * 64];
  __shared__ u16 Vs[2][64 * 64];
  const int tid = threadIdx.x;
  const int w = tid >> 6, lane = tid & 63;
  const int wq = w >> 1, wk = w & 1;
  const int l15 = lane & 15, quad = lane >> 4;

  // XCD-aware remap: xcd = orig%8 (dispatch round-robin); each xcd gets a
  // contiguous swz-range of 128 = 4 complete (b,h) groups of 32 q-blocks.
  const int orig = blockIdx.x;
  const int swz = (orig & 7) * 128 + (orig >> 3);
  const int q0 = (swz & 31) * 64;
  const int bh = swz >> 5;
  const int h = bh & 15, b = bh >> 4;

  short8 qf[2][2];
#pragma unroll
  for (int rt = 0; rt < 2; rt++) {
    const u16* qbase = qkv + (size_t)(b * S_ + q0 + wq * 32 + rt * 16 + l15) * 3072 + h * 64;
    qf[rt][0] = *(const short8*)(qbase + quad * 8);
    qf[rt][1] = *(const short8*)(qbase + 32 + quad * 8);
  }

  const int col0 = ((quad ^ (l15 & 7)) & 7) * 8;
  const int col1 = (((4 + quad) ^ (l15 & 7)) & 7) * 8;
  const int colw = wk ? col1 : col0;  // this wave's s-slice of V

  int r_st[2], cs_st[2];
#pragma unroll
  for (int i = 0; i < 2; i++) {
    int idx = i * 256 + tid;
    r_st[i] = idx >> 3;
    cs_st[i] = ((idx & 7) ^ (r_st[i] & 7)) * 8;
  }
  const u16* kp[2];
  const u16* vp[2];
#pragma unroll
  for (int i = 0; i < 2; i++) {
    kp[i] = qkv + (size_t)(b * S_ + r_st[i]) * 3072 + 1024 + h * 64 + cs_st[i];
    vp[i] = Vt + ((size_t)(b * H_ + h) * 64 + r_st[i]) * S_ + cs_st[i];
  }

  const f32x4 zero = {0.f, 0.f, 0.f, 0.f};
  f32x4 o[2][4];
#pragma unroll
  for (int rt = 0; rt < 2; rt++)
#pragma unroll
    for (int i = 0; i < 4; i++) o[rt][i] = zero;
  float lsum[2] = {0.f, 0.f};

  auto stage = [&](int bb, int t) {
#pragma unroll
    for (int i = 0; i < 2; i++) {
      gll16(kp[i] + (size_t)t * 64 * 3072, &Ks[bb][(i * 256 + w * 64) * 8]);
      gll16(vp[i] + t * 64, &Vs[bb][(i * 256 + w * 64) * 8]);
    }
  };

  auto compute = [&](int bb) {
    short8 kf[2][2];
#pragma unroll
    for (int kb = 0; kb < 2; kb++) {
      const int krow = (wk * 32 + kb * 16 + l15) * 64;
      kf[kb][0] = *(const short8*)&Ks[bb][krow + col0];
      kf[kb][1] = *(const short8*)&Ks[bb][krow + col1];
    }
    short8 pf[2];
#pragma unroll
    for (int rt = 0; rt < 2; rt++) {
      uint32_t Sx[2][2];
      __builtin_amdgcn_s_setprio(1);
#pragma unroll
      for (int kb = 0; kb < 2; kb++) {
        f32x4 st = __builtin_amdgcn_mfma_f32_16x16x32_bf16(kf[kb][0], qf[rt][0], zero, 0, 0, 0);
        st = __builtin_amdgcn_mfma_f32_16x16x32_bf16(kf[kb][1], qf[rt][1], st, 0, 0, 0);
        __builtin_amdgcn_s_setprio(0);
        float p0 = fexp2(st[0]), p1 = fexp2(st[1]), p2 = fexp2(st[2]), p3 = fexp2(st[3]);
        lsum[rt] += (p0 + p1) + (p2 + p3);
        Sx[kb][0] = pk_bf16(p0, p1);  // k = kb*16 + quad*4 + {0,1}
        Sx[kb][1] = pk_bf16(p2, p3);  // k = kb*16 + quad*4 + {2,3}
      }
#pragma unroll
      for (int s = 0; s < 2; s++)
        asm volatile("v_permlane32_swap_b32 %0, %1" : "+v"(Sx[0][s]), "+v"(Sx[1][s]));
#pragma unroll
      for (int s = 0; s < 2; s++)
        asm volatile("v_permlane16_swap_b32 %0, %1" : "+v"(Sx[0][s]), "+v"(Sx[1][s]));
      union { uint32_t u[4]; short8 s8; } cv;
      cv.u[0] = Sx[0][0]; cv.u[1] = Sx[0][1];
      cv.u[2] = Sx[1][0]; cv.u[3] = Sx[1][1];
      pf[rt] = cv.s8;
    }
    __builtin_amdgcn_s_setprio(1);
#pragma unroll
    for (int vi = 0; vi < 4; vi++) {
      short8 vf = *(const short8*)&Vs[bb][(vi * 16 + l15) * 64 + colw];
      o[0][vi] = __builtin_amdgcn_mfma_f32_16x16x32_bf16(vf, pf[0], o[0][vi], 0, 0, 0);
      o[1][vi] = __builtin_amdgcn_mfma_f32_16x16x32_bf16(vf, pf[1], o[1][vi], 0, 0, 0);
    }
    __builtin_amdgcn_s_setprio(0);
  };

  stage(0, 0);
  for (int t = 0; t < 31; t++) {
    __syncthreads();
    stage((t + 1) & 1, t + 1);
    compute(t & 1);
  }
  __syncthreads();
  compute(1);

  // ---- cross-wave (wk) reduction of O and lsum through freed LDS ----
  float ls[2];
#pragma unroll
  for (int rt = 0; rt < 2; rt++) {
    float l = lsum[rt];
    l += __shfl_xor(l, 16);
    l += __shfl_xor(l, 32);
    ls[rt] = l;
  }
  __syncthreads();  // all compute reads of Ks/Vs done before reuse
  float* red = (float*)&Ks[0][0];   // 16 KB: 2 wq-waves x 8 KB
  float* redl = (float*)&Vs[0][0];  // 1 KB
  if (wk == 1) {
#pragma unroll
    for (int rt = 0; rt < 2; rt++) {
#pragma unroll
      for (int vi = 0; vi < 4; vi++)
        *(f32x4*)(red + wq * 2048 + (rt * 4 + vi) * 256 + lane * 4) = o[rt][vi];
      redl[wq * 128 + rt * 64 + lane] = ls[rt];
    }
  }
  __syncthreads();
  if (wk == 0) {
#pragma unroll
    for (int rt = 0; rt < 2; rt++) {
      const float tot = ls[rt] + redl[wq * 128 + rt * 64 + lane];
      const float inv = 1.f / tot;
      u16* cbase = ctx + (size_t)(b * S_ + q0 + wq * 32 + rt * 16 + l15) * 1024 + h * 64;
#pragma unroll
      for (int vi = 0; vi < 4; vi++) {
        f32x4 p = *(f32x4*)(red + wq * 2048 + (rt * 4 + vi) * 256 + lane * 4);
        f32x4 s = o[rt][vi] + p;
        ushort4 pk;
        pk.x = f2bf(s[0] * inv);
        pk.y = f2bf(s[1] * inv);
        pk.z = f2bf(s[2] * inv);
        pk.w = f2bf(s[3] * inv);
        *(ushort4*)(cbase + vi * 16 + quad * 4) = pk;
      }
    }
  }
}

extern "C" void kernel_launch(void* const* d_in, const int* in_sizes, int n_in,
                              void* d_out, int out_size, void* d_ws, size_t ws_size,
                              hipStream_t stream) {
  const float* hidden = (const float*)d_in[0];
  const float* Wq = (const float*)d_in[1];
  const float* bq = (const float*)d_in[2];
  const float* Wk = (const float*)d_in[3];
  const float* bk = (const float*)d_in[4];
  const float* Wv = (const float*)d_in[5];
  const float* bv = (const float*)d_in[6];
  const float* Wo = (const float*)d_in[7];
  const float* bo = (const float*)d_in[8];
  float* out = (float*)d_out;

  char* ws = (char*)d_ws;
  u16* Abf = (u16*)(ws + 0);                 // 4096x1024 bf16   (8,388,608)
  u16* Wt = (u16*)(ws + 8388608);            // 3072x1024 bf16   (6,291,456)
  u16* Wot = (u16*)(ws + 14680064);          // 1024x1024 bf16   (2,097,152)
  float* biasQKV = (float*)(ws + 16777216);  // 3072 fp32        (12,288 padded)
  u16* qkv = (u16*)(ws + 16789504);          // 4096x3072 bf16   (25,165,824; V third unused)
  u16* Vt = (u16*)(ws + 41955328);           // [b][h][64][2048] (8,388,608)
  u16* ctx = (u16*)(ws + 50343936);          // 4096x1024 bf16   (8,388,608)

  // fused prep: cast + Wq/Wk/Wv transpose + bias + Wo transpose
  prep_k<<<3072, 256, 0, stream>>>(hidden, Wq, Wk, Wv, bq, bk, bv, Wo,
                                   Abf, Wt, Wot, biasQKV);

  // QKV projection: [4096,1024] x [3072,1024]^T -> qkv (Q,K) + Vt (V, fused
  // transpose). Flat grid 768, XCD decode inside; counted-vmcnt dbuf (T4).
  gemm_bt_k<<<dim3(768), 256, 0, stream>>>(Abf, Wt, biasQKV, qkv, Vt, 4096, 3072, 1024);

  // flash attention -> ctx [4096, 1024] bf16  (flat grid, XCD-aware swizzle)
  attn_k<<<dim3(1024), 256, 0, stream>>>(qkv, Vt, ctx);

  // output projection: [4096,1024] x [1024,1024]^T + bo -> fp32 out
  // (BK=64, counted-vmcnt dbuf, count=6)
  gemm_bt64_k<<<dim3(512), 256, 0, stream>>>(ctx, Wot, bo, out, 4096, 1024, 1024);
}